// Round 9
// baseline (301.261 us; speedup 1.0000x reference)
//
#include <hip/hip_runtime.h>

typedef unsigned int   u32;
typedef unsigned short u16;
typedef __attribute__((ext_vector_type(8))) short short8;
typedef __attribute__((ext_vector_type(4))) float f32x4;

// B=64 T=256 C=512 H=8 D=64; M = B*T = 16384; K = 512; Nqkv = 1536

__device__ __forceinline__ u16 f2bf(float f) {
    u32 u = __float_as_uint(f);
    u += 0x7fffu + ((u >> 16) & 1u);   // RNE
    return (u16)(u >> 16);
}

// ---------------- cast x (fp32 -> bf16) ----------------
__global__ void cast_x_kernel(const float* __restrict__ x, u16* __restrict__ xb) {
    int i = blockIdx.x * 256 + threadIdx.x;
    float4 v = ((const float4*)x)[i];
    ushort4 o;
    o.x = f2bf(v.x); o.y = f2bf(v.y); o.z = f2bf(v.z); o.w = f2bf(v.w);
    ((ushort4*)xb)[i] = o;
}

// -------- pack wq|wk|wv -> bf16 [1536][512] transposed --------
__global__ void pack_wqkv_kernel(const float* __restrict__ wq, const float* __restrict__ wk,
                                 const float* __restrict__ wv, u16* __restrict__ wt) {
    int i = blockIdx.x * 256 + threadIdx.x;
    int n = i >> 9, c = i & 511;
    int proj = n >> 9, hd = n & 511;
    int h = hd >> 6, d = hd & 63;
    const float* w = (proj == 0) ? wq : (proj == 1) ? wk : wv;
    wt[(size_t)n * 512 + c] = f2bf(w[h * 32768 + c * 64 + d]);
}

// -------- pack wo [512][512] -> bf16 transposed [n][k] --------
__global__ void pack_wo_kernel(const float* __restrict__ wo, u16* __restrict__ wt) {
    int i = blockIdx.x * 256 + threadIdx.x;
    int n = i >> 9, k = i & 511;
    wt[(size_t)n * 512 + k] = f2bf(wo[(size_t)k * 512 + n]);
}

// ---------------- register-streaming GEMM helpers ----------------
// TN layout: both A[m][k] and Bt[n][k] are row-major with k contiguous, so
// MFMA fragments (16B k-runs) are loaded DIRECTLY from global into VGPRs.
// No LDS, no __syncthreads, no cross-wave convoy: each wave's vmcnt waits
// are private and software-pipelined one k-tile ahead (R8 post-mortem: the
// 2-barrier LDS structure is plateaued at ~350 TF for 16-iter K-loops).
__device__ __forceinline__ void ldf(const u16* Ap0, const u16* Bp0, int kt,
                                    short8* af, short8* bf) {
    #pragma unroll
    for (int mi = 0; mi < 4; ++mi) af[mi] = *(const short8*)(Ap0 + mi * 8192 + kt * 32);
    #pragma unroll
    for (int ni = 0; ni < 4; ++ni) bf[ni] = *(const short8*)(Bp0 + ni * 8192 + kt * 32);
}
__device__ __forceinline__ void mm16(const short8* af, const short8* bf, f32x4 acc[4][4]) {
    #pragma unroll
    for (int mi = 0; mi < 4; ++mi)
        #pragma unroll
        for (int ni = 0; ni < 4; ++ni)
            acc[mi][ni] = __builtin_amdgcn_mfma_f32_16x16x32_bf16(af[mi], bf[ni], acc[mi][ni], 0, 0, 0);
}

// ---------------- QKV GEMM: 128x128 block, 64x64 wave tile, K=512 ----------
// XCD swizzle: XCD x owns m-stripes [x*16,(x+1)*16) for all 12 n-tiles
// (A-chunk 2MB + B 1.5MB per XCD L2). Epilogue scatters Q,K to [head][t][d]
// and V transposed to Vt [head][d][t].
__global__ __launch_bounds__(256)
void gemm_qkv(const u16* __restrict__ A, const u16* __restrict__ Bt,
              u16* __restrict__ Qb, u16* __restrict__ Kb, u16* __restrict__ Vb,
              const float* __restrict__ bq, const float* __restrict__ bk,
              const float* __restrict__ bv) {
    const int tid = threadIdx.x;
    const int bid = blockIdx.x;
    const int xcd = bid & 7;
    const int k8  = bid >> 3;                 // 0..191
    const int m0 = (xcd * 16 + k8 / 12) * 128;
    const int n0 = (k8 % 12) * 128;
    const int w = tid >> 6, lane = tid & 63;
    const int wrow = (w >> 1) * 64, wcol = (w & 1) * 64;
    const int lm = lane & 15, quad = lane >> 4;

    const u16* Ap0 = A  + (size_t)(m0 + wrow + lm) * 512 + quad * 8;
    const u16* Bp0 = Bt + (size_t)(n0 + wcol + lm) * 512 + quad * 8;

    f32x4 acc[4][4] = {};
    short8 aA[4], bA[4], aB[4], bB[4];
    ldf(Ap0, Bp0, 0, aA, bA);
    #pragma unroll
    for (int kt = 0; kt < 16; kt += 2) {
        if (kt + 1 < 16) ldf(Ap0, Bp0, kt + 1, aB, bB);
        mm16(aA, bA, acc);
        if (kt + 2 < 16) ldf(Ap0, Bp0, kt + 2, aA, bA);
        mm16(aB, bB, acc);
    }

    #pragma unroll
    for (int ni = 0; ni < 4; ++ni) {
        int ncol = n0 + wcol + ni * 16 + lm;
        int proj = ncol >> 9, hd = ncol & 511;
        int h = hd >> 6, d = hd & 63;
        const float* bptr = (proj == 0) ? bq : (proj == 1) ? bk : bv;
        u16* dst = (proj == 0) ? Qb : (proj == 1) ? Kb : Vb;
        float bias = bptr[hd];
        #pragma unroll
        for (int mi = 0; mi < 4; ++mi) {
            int mbase = m0 + wrow + mi * 16 + quad * 4;
            #pragma unroll
            for (int r = 0; r < 4; ++r) {
                int mrow = mbase + r;
                int b = mrow >> 8, t = mrow & 255;
                size_t idx = (proj == 2)
                    ? ((size_t)((b * 8 + h) * 64 + d) * 256 + t)     // Vt [head][d][t]
                    : ((size_t)((b * 8 + h) * 256 + t) * 64 + d);   // Q/K [head][t][d]
                dst[idx] = f2bf(acc[mi][ni][r] + bias);
            }
        }
    }
}

// ---------------- out-proj GEMM: 128x128 block, 64x64 wave tile -------------
__global__ __launch_bounds__(256)
void gemm_out(const u16* __restrict__ A, const u16* __restrict__ Bt,
              float* __restrict__ outf, const float* __restrict__ bo) {
    const int tid = threadIdx.x;
    const int bid = blockIdx.x;
    const int xcd = bid & 7;
    const int k8  = bid >> 3;                 // 0..63
    const int m0 = (xcd * 16 + k8 / 4) * 128;
    const int n0 = (k8 % 4) * 128;
    const int w = tid >> 6, lane = tid & 63;
    const int wrow = (w >> 1) * 64, wcol = (w & 1) * 64;
    const int lm = lane & 15, quad = lane >> 4;

    const u16* Ap0 = A  + (size_t)(m0 + wrow + lm) * 512 + quad * 8;
    const u16* Bp0 = Bt + (size_t)(n0 + wcol + lm) * 512 + quad * 8;

    f32x4 acc[4][4] = {};
    short8 aA[4], bA[4], aB[4], bB[4];
    ldf(Ap0, Bp0, 0, aA, bA);
    #pragma unroll
    for (int kt = 0; kt < 16; kt += 2) {
        if (kt + 1 < 16) ldf(Ap0, Bp0, kt + 1, aB, bB);
        mm16(aA, bA, acc);
        if (kt + 2 < 16) ldf(Ap0, Bp0, kt + 2, aA, bA);
        mm16(aB, bB, acc);
    }

    #pragma unroll
    for (int ni = 0; ni < 4; ++ni) {
        int ncol = n0 + wcol + ni * 16 + lm;
        float bias = bo[ncol];
        #pragma unroll
        for (int mi = 0; mi < 4; ++mi) {
            int mbase = m0 + wrow + mi * 16 + quad * 4;
            #pragma unroll
            for (int r = 0; r < 4; ++r)
                outf[(size_t)(mbase + r) * 512 + ncol] = acc[mi][ni][r] + bias;
        }
    }
}

// ---------------- MFMA flash attention (global K and V, LDS = P only) -------
// TWO wgs per (b,h) (iset 0: i in {0,3}; iset 1: i in {1,2}), XCD-co-located.
// K and V fragments read DIRECTLY from global (Kb[head][t][d] and
// Vt[head][d][t] are both fragment-contiguous; 32KB each, L2-resident).
// LDS = 8KB P buffers only -> all 1024 wgs resident. One barrier per j-tile
// (P C/D->A-layout round-trip ordering).
__global__ __launch_bounds__(256)
void attn_mfma_kernel(const u16* __restrict__ Qg, const u16* __restrict__ Kg,
                      const u16* __restrict__ Vtg, u16* __restrict__ attn) {
    __shared__ __align__(16) u16 lds[4096];   // P: w*1024
    const int bid = blockIdx.x;
    const int head = (bid & 7) * 64 + ((bid >> 3) >> 1);
    const int iset = (bid >> 3) & 1;
    const int b = head >> 3, h = head & 7;
    const int tid = threadIdx.x;
    const size_t hb = (size_t)head * 16384;

    const int w = tid >> 6, lane = tid & 63;
    const int lm = lane & 15, quad = lane >> 4;
    const int l7 = lm & 7;

    const u16* Kgh = Kg + hb;                 // [t][d]
    const u16* Vg  = Vtg + hb;                // [d][t]
    const int Pbase = w * 1024;
    const int x0 = (lm >> 3) & 1;
    const int pw_even = Pbase + quad * 16 + l7 + x0 * 8;
    const int pw_odd  = Pbase + quad * 16 + l7 + (x0 ^ 1) * 8;
    const int pr0 = Pbase + ((lm & 3) * 4 + (quad >> 1)) * 64
                  + (2 * (lm >> 2) + ((quad & 1) ^ (lm & 1))) * 8;

    #pragma unroll 1
    for (int ii = 0; ii < 2; ++ii) {
        const int i = iset ? (ii ? 2 : 1) : (ii ? 3 : 0);
        const int t0 = i * 64 + w * 16;
        short8 qa0 = *(const short8*)(Qg + hb + (size_t)(t0 + lm) * 64 + quad * 8);
        short8 qa1 = *(const short8*)(Qg + hb + (size_t)(t0 + lm) * 64 + 32 + quad * 8);
        f32x4 O[4] = {};
        float mr[4] = {-INFINITY, -INFINITY, -INFINITY, -INFINITY};
        float lr[4] = {0.f, 0.f, 0.f, 0.f};

        #pragma unroll 1
        for (int j = 0; j <= i; ++j) {
            f32x4 S[4] = {};
            #pragma unroll
            for (int ni = 0; ni < 4; ++ni) {
                const u16* kp = Kgh + (size_t)(j * 64 + ni * 16 + lm) * 64;
                short8 kb0 = *(const short8*)(kp + quad * 8);
                short8 kb1 = *(const short8*)(kp + 32 + quad * 8);
                S[ni] = __builtin_amdgcn_mfma_f32_16x16x32_bf16(qa0, kb0, S[ni], 0, 0, 0);
                S[ni] = __builtin_amdgcn_mfma_f32_16x16x32_bf16(qa1, kb1, S[ni], 0, 0, 0);
            }
            // hoisted V-fragment loads (P-independent; overlap softmax+barrier)
            short8 vb[4][2];
            #pragma unroll
            for (int nd = 0; nd < 4; ++nd) {
                const u16* vp = Vg + (size_t)(nd * 16 + lm) * 256 + j * 64;
                vb[nd][0] = *(const short8*)(vp + quad * 8);
                vb[nd][1] = *(const short8*)(vp + 32 + quad * 8);
            }
            if (j == i) {
                #pragma unroll
                for (int ni = 0; ni < 4; ++ni) {
                    int scol = ni * 16 + lm;
                    #pragma unroll
                    for (int rr = 0; rr < 4; ++rr) {
                        int tloc = w * 16 + quad * 4 + rr;
                        S[ni][rr] = (scol > tloc) ? -INFINITY : S[ni][rr] * 0.125f;
                    }
                }
            } else {
                #pragma unroll
                for (int ni = 0; ni < 4; ++ni)
                    #pragma unroll
                    for (int rr = 0; rr < 4; ++rr)
                        S[ni][rr] *= 0.125f;
            }
            float alpha[4];
            #pragma unroll
            for (int rr = 0; rr < 4; ++rr) {
                float mx = fmaxf(fmaxf(S[0][rr], S[1][rr]), fmaxf(S[2][rr], S[3][rr]));
                mx = fmaxf(mx, __shfl_xor(mx, 1));
                mx = fmaxf(mx, __shfl_xor(mx, 2));
                mx = fmaxf(mx, __shfl_xor(mx, 4));
                mx = fmaxf(mx, __shfl_xor(mx, 8));
                float mnew = fmaxf(mr[rr], mx);
                alpha[rr] = __expf(mr[rr] - mnew);
                mr[rr] = mnew;
            }
            float rs[4] = {0.f, 0.f, 0.f, 0.f};
            #pragma unroll
            for (int ni = 0; ni < 4; ++ni) {
                #pragma unroll
                for (int rr = 0; rr < 4; ++rr) {
                    float p = __expf(S[ni][rr] - mr[rr]);
                    rs[rr] += p;
                    int addr = ((rr & 1) ? pw_odd : pw_even) + (rr * 4 + ni) * 64;
                    lds[addr] = f2bf(p);
                }
            }
            #pragma unroll
            for (int rr = 0; rr < 4; ++rr) {
                float s = rs[rr];
                s += __shfl_xor(s, 1);
                s += __shfl_xor(s, 2);
                s += __shfl_xor(s, 4);
                s += __shfl_xor(s, 8);
                lr[rr] = lr[rr] * alpha[rr] + s;
                O[0][rr] *= alpha[rr]; O[1][rr] *= alpha[rr];
                O[2][rr] *= alpha[rr]; O[3][rr] *= alpha[rr];
            }
            __syncthreads();   // P write -> read ordering
            short8 pa0 = *(const short8*)(lds + pr0);
            short8 pa1 = *(const short8*)(lds + pr0 + 128);
            #pragma unroll
            for (int nd = 0; nd < 4; ++nd) {
                O[nd] = __builtin_amdgcn_mfma_f32_16x16x32_bf16(pa0, vb[nd][0], O[nd], 0, 0, 0);
                O[nd] = __builtin_amdgcn_mfma_f32_16x16x32_bf16(pa1, vb[nd][1], O[nd], 0, 0, 0);
            }
        }
        #pragma unroll
        for (int rr = 0; rr < 4; ++rr) {
            float inv = 1.0f / lr[rr];
            int t = t0 + quad * 4 + rr;
            u16* op = attn + (size_t)(b * 256 + t) * 512 + h * 64 + lm;
            op[0]  = f2bf(O[0][rr] * inv);
            op[16] = f2bf(O[1][rr] * inv);
            op[32] = f2bf(O[2][rr] * inv);
            op[48] = f2bf(O[3][rr] * inv);
        }
    }
}

extern "C" void kernel_launch(void* const* d_in, const int* in_sizes, int n_in,
                              void* d_out, int out_size, void* d_ws, size_t ws_size,
                              hipStream_t stream) {
    const float* x  = (const float*)d_in[0];
    const float* wq = (const float*)d_in[1];
    const float* wk = (const float*)d_in[2];
    const float* wv = (const float*)d_in[3];
    const float* bq = (const float*)d_in[4];
    const float* bk = (const float*)d_in[5];
    const float* bv = (const float*)d_in[6];
    const float* wo = (const float*)d_in[7];
    const float* bo = (const float*)d_in[8];
    float* out = (float*)d_out;

    char* ws = (char*)d_ws;
    const size_t SZ = 16777216;                  // 16384*512*2 bytes
    u16* xb    = (u16*)(ws);
    u16* Qb    = (u16*)(ws + SZ);
    u16* Kb    = (u16*)(ws + 2 * SZ);
    u16* Vt    = (u16*)(ws + 3 * SZ);            // [head][d][t]
    u16* attn  = (u16*)(ws + 4 * SZ);
    u16* wqkvT = (u16*)(ws + 5 * SZ);
    u16* woT   = (u16*)(ws + 5 * SZ + 1572864);

    cast_x_kernel<<<8192, 256, 0, stream>>>(x, xb);
    pack_wqkv_kernel<<<3072, 256, 0, stream>>>(wq, wk, wv, wqkvT);
    pack_wo_kernel<<<1024, 256, 0, stream>>>(wo, woT);

    gemm_qkv<<<1536, 256, 0, stream>>>(xb, wqkvT, Qb, Kb, Vt, bq, bk, bv);

    attn_mfma_kernel<<<1024, 256, 0, stream>>>(Qb, Kb, Vt, attn);

    gemm_out<<<512, 256, 0, stream>>>(attn, woT, out, bo);
}

// Round 10
// 215.636 us; speedup vs baseline: 1.3971x; 1.3971x over previous
//
#include <hip/hip_runtime.h>

typedef unsigned int   u32;
typedef unsigned short u16;
typedef __attribute__((ext_vector_type(8))) short short8;
typedef __attribute__((ext_vector_type(4))) float f32x4;

// B=64 T=256 C=512 H=8 D=64; M = B*T = 16384; K = 512; Nqkv = 1536

__device__ __forceinline__ u16 f2bf(float f) {
    u32 u = __float_as_uint(f);
    u += 0x7fffu + ((u >> 16) & 1u);   // RNE
    return (u16)(u >> 16);
}

// async global->LDS 16B DMA; LDS dest must be wave-uniform base + lane*16.
__device__ __forceinline__ void gload_lds16(const u16* g, u16* l) {
    __builtin_amdgcn_global_load_lds(
        (const __attribute__((address_space(1))) u32*)(const void*)g,
        (__attribute__((address_space(3))) u32*)(void*)l, 16, 0, 0);
}

// ---------------- cast x (fp32 -> bf16) ----------------
__global__ void cast_x_kernel(const float* __restrict__ x, u16* __restrict__ xb) {
    int i = blockIdx.x * 256 + threadIdx.x;
    float4 v = ((const float4*)x)[i];
    ushort4 o;
    o.x = f2bf(v.x); o.y = f2bf(v.y); o.z = f2bf(v.z); o.w = f2bf(v.w);
    ((ushort4*)xb)[i] = o;
}

// -------- pack wq|wk|wv -> bf16 [1536][512] transposed --------
__global__ void pack_wqkv_kernel(const float* __restrict__ wq, const float* __restrict__ wk,
                                 const float* __restrict__ wv, u16* __restrict__ wt) {
    int i = blockIdx.x * 256 + threadIdx.x;
    int n = i >> 9, c = i & 511;
    int proj = n >> 9, hd = n & 511;
    int h = hd >> 6, d = hd & 63;
    const float* w = (proj == 0) ? wq : (proj == 1) ? wk : wv;
    wt[(size_t)n * 512 + c] = f2bf(w[h * 32768 + c * 64 + d]);
}

// -------- pack wo [512][512] -> bf16 transposed [n][k] --------
__global__ void pack_wo_kernel(const float* __restrict__ wo, u16* __restrict__ wt) {
    int i = blockIdx.x * 256 + threadIdx.x;
    int n = i >> 9, k = i & 511;
    wt[(size_t)n * 512 + k] = f2bf(wo[(size_t)k * 512 + n]);
}

// ---------------- 128x128 bf16 MFMA GEMM, K=512, TN ----------------
// ROTATING 3-BUFFER staging (48KB LDS): the functional point is residency
// throttling — 160/48 = 3 blocks/CU (was 6 at 16-32KB). Every epoch ends in a
// vmcnt(0) drain that waits behind ALL co-resident blocks' DMA queues; m97
// data (3 blocks/CU -> ~740 cyc/epoch) vs R6 (6 blocks/CU -> ~1750) says
// fewer residents = shorter queues = faster epochs. Prefetch 1 ahead.
// Chunk swizzle slot=c^((r>>1)&3): conflict-free (R6: 3.1M -> 0).
// XCD swizzle: XCD x owns m-stripes [x*16,(x+1)*16) for all NT n-tiles.
template<int EPI, int NT>
__global__ __launch_bounds__(256)
void gemm128_kernel(const u16* __restrict__ A, const u16* __restrict__ Bt,
                    float* __restrict__ outf, const float* __restrict__ bo,
                    u16* __restrict__ Qb, u16* __restrict__ Kb, u16* __restrict__ Vb,
                    const float* __restrict__ bq, const float* __restrict__ bk,
                    const float* __restrict__ bv) {
    __shared__ __align__(16) u16 As[3][128 * 32];
    __shared__ __align__(16) u16 Bs[3][128 * 32];
    const int tid = threadIdx.x;
    const int bid = blockIdx.x;
    const int xcd = bid & 7;
    const int k8  = bid >> 3;                 // 0 .. 16*NT-1
    const int m0 = (xcd * 16 + k8 / NT) * 128;
    const int n0 = (k8 % NT) * 128;
    const int lrow = tid >> 2;            // 0..63
    const int seg  = tid & 3;
    const int xsw  = (lrow >> 1) & 3;     // chunk-xor (same for row lrow+64)
    const u16* Ag = A  + (size_t)(m0 + lrow) * 512 + (seg ^ xsw) * 8;
    const u16* Bg = Bt + (size_t)(n0 + lrow) * 512 + (seg ^ xsw) * 8;
    const int lofs = lrow * 32 + seg * 8;

    const int w = tid >> 6, lane = tid & 63;
    const int wrow = (w >> 1) * 64, wcol = (w & 1) * 64;
    const int lm = lane & 15, quad = lane >> 4;
    const int kx = (quad ^ ((lm >> 1) & 3)) * 8;   // frag chunk position

    f32x4 acc[4][4] = {};

    // prologue: stage tile 0 into buffer 0
    gload_lds16(Ag,            As[0] + lofs);
    gload_lds16(Ag + 64 * 512, As[0] + lofs + 64 * 32);
    gload_lds16(Bg,            Bs[0] + lofs);
    gload_lds16(Bg + 64 * 512, Bs[0] + lofs + 64 * 32);

    #pragma unroll 1
    for (int kt = 0; kt < 16; ++kt) {
        __syncthreads();   // tile kt DMA complete; buffer (kt+1)%3's old reads done
        if (kt < 15) {     // prefetch tile kt+1
            const u16* Agp = Ag + (kt + 1) * 32;
            const u16* Bgp = Bg + (kt + 1) * 32;
            u16* Asp = As[(kt + 1) % 3] + lofs;
            u16* Bsp = Bs[(kt + 1) % 3] + lofs;
            gload_lds16(Agp,            Asp);
            gload_lds16(Agp + 64 * 512, Asp + 64 * 32);
            gload_lds16(Bgp,            Bsp);
            gload_lds16(Bgp + 64 * 512, Bsp + 64 * 32);
        }
        const u16* Ac = As[kt % 3];
        const u16* Bc = Bs[kt % 3];
        short8 af[4], bf[4];
        #pragma unroll
        for (int mi = 0; mi < 4; ++mi)
            af[mi] = *(const short8*)(Ac + (wrow + mi * 16 + lm) * 32 + kx);
        #pragma unroll
        for (int ni = 0; ni < 4; ++ni)
            bf[ni] = *(const short8*)(Bc + (wcol + ni * 16 + lm) * 32 + kx);
        #pragma unroll
        for (int mi = 0; mi < 4; ++mi)
            #pragma unroll
            for (int ni = 0; ni < 4; ++ni)
                acc[mi][ni] = __builtin_amdgcn_mfma_f32_16x16x32_bf16(af[mi], bf[ni], acc[mi][ni], 0, 0, 0);
    }

    if (EPI == 1) {
        #pragma unroll
        for (int ni = 0; ni < 4; ++ni) {
            int ncol = n0 + wcol + ni * 16 + lm;
            float bias = bo[ncol];
            #pragma unroll
            for (int mi = 0; mi < 4; ++mi) {
                int mbase = m0 + wrow + mi * 16 + quad * 4;
                #pragma unroll
                for (int r = 0; r < 4; ++r)
                    outf[(size_t)(mbase + r) * 512 + ncol] = acc[mi][ni][r] + bias;
            }
        }
    } else {
        #pragma unroll
        for (int ni = 0; ni < 4; ++ni) {
            int ncol = n0 + wcol + ni * 16 + lm;
            int proj = ncol >> 9, hd = ncol & 511;
            int h = hd >> 6, d = hd & 63;
            const float* bptr = (proj == 0) ? bq : (proj == 1) ? bk : bv;
            u16* dst = (proj == 0) ? Qb : (proj == 1) ? Kb : Vb;
            float bias = bptr[hd];
            #pragma unroll
            for (int mi = 0; mi < 4; ++mi) {
                int mbase = m0 + wrow + mi * 16 + quad * 4;
                #pragma unroll
                for (int r = 0; r < 4; ++r) {
                    int mrow = mbase + r;
                    int b = mrow >> 8, t = mrow & 255;
                    size_t idx = (proj == 2)
                        ? ((size_t)((b * 8 + h) * 64 + d) * 256 + t)     // Vt [head][d][t]
                        : ((size_t)((b * 8 + h) * 256 + t) * 64 + d);   // Q/K [head][t][d]
                    dst[idx] = f2bf(acc[mi][ni][r] + bias);
                }
            }
        }
    }
}

// ---------------- MFMA flash attention (R8 form — best verified) ------------
// TWO wgs per (b,h) (iset 0: i in {0,3}; iset 1: i in {1,2}), XCD-co-located.
// K staged in LDS (XOR 16B-chunk swizzle, conflict-free); V fragments read
// directly from global Vt[head][d][t], hoisted above softmax (P-independent;
// L2 latency overlaps softmax+barrier). LDS 40KB/wg -> 4 wg/CU.
__global__ __launch_bounds__(256)
void attn_mfma_kernel(const u16* __restrict__ Qg, const u16* __restrict__ Kg,
                      const u16* __restrict__ Vtg, u16* __restrict__ attn) {
    __shared__ __align__(16) u16 lds[20480];   // K:0..16383 | P: 16384 + w*1024
    const int bid = blockIdx.x;
    const int head = (bid & 7) * 64 + ((bid >> 3) >> 1);
    const int iset = (bid >> 3) & 1;
    const int b = head >> 3, h = head & 7;
    const int tid = threadIdx.x;
    const size_t hb = (size_t)head * 16384;

    {
        const uint4* Ksrc = (const uint4*)(Kg + hb);
        uint4* L4 = (uint4*)lds;
        #pragma unroll
        for (int it = 0; it < 8; ++it) {
            int g = it * 256 + tid;
            int kr = g >> 3, kc = g & 7;
            L4[kr * 8 + (kc ^ (kr & 7))] = Ksrc[g];
        }
    }
    __syncthreads();

    const int w = tid >> 6, lane = tid & 63;
    const int lm = lane & 15, quad = lane >> 4;
    const int l7 = lm & 7;

    const int kx0 = (quad ^ l7) * 8;
    const int kx1 = ((4 + quad) ^ l7) * 8;
    const u16* Kbase = lds + lm * 64;
    const u16* Vg = Vtg + hb;
    const int Pbase = 16384 + w * 1024;
    const int x0 = (lm >> 3) & 1;
    const int pw_even = Pbase + quad * 16 + l7 + x0 * 8;
    const int pw_odd  = Pbase + quad * 16 + l7 + (x0 ^ 1) * 8;
    const int pr0 = Pbase + ((lm & 3) * 4 + (quad >> 1)) * 64
                  + (2 * (lm >> 2) + ((quad & 1) ^ (lm & 1))) * 8;

    #pragma unroll 1
    for (int ii = 0; ii < 2; ++ii) {
        const int i = iset ? (ii ? 2 : 1) : (ii ? 3 : 0);
        const int t0 = i * 64 + w * 16;
        short8 qa0 = *(const short8*)(Qg + hb + (size_t)(t0 + lm) * 64 + quad * 8);
        short8 qa1 = *(const short8*)(Qg + hb + (size_t)(t0 + lm) * 64 + 32 + quad * 8);
        f32x4 O[4] = {};
        float mr[4] = {-INFINITY, -INFINITY, -INFINITY, -INFINITY};
        float lr[4] = {0.f, 0.f, 0.f, 0.f};

        #pragma unroll 1
        for (int j = 0; j <= i; ++j) {
            f32x4 S[4] = {};
            #pragma unroll
            for (int ni = 0; ni < 4; ++ni) {
                const u16* kp = Kbase + j * 4096 + ni * 1024;
                short8 kb0 = *(const short8*)(kp + kx0);
                short8 kb1 = *(const short8*)(kp + kx1);
                S[ni] = __builtin_amdgcn_mfma_f32_16x16x32_bf16(qa0, kb0, S[ni], 0, 0, 0);
                S[ni] = __builtin_amdgcn_mfma_f32_16x16x32_bf16(qa1, kb1, S[ni], 0, 0, 0);
            }
            // hoisted V-fragment loads (P-independent; overlap softmax+barrier)
            short8 vb[4][2];
            #pragma unroll
            for (int nd = 0; nd < 4; ++nd) {
                const u16* vp = Vg + (size_t)(nd * 16 + lm) * 256 + j * 64;
                vb[nd][0] = *(const short8*)(vp + quad * 8);
                vb[nd][1] = *(const short8*)(vp + 32 + quad * 8);
            }
            if (j == i) {
                #pragma unroll
                for (int ni = 0; ni < 4; ++ni) {
                    int scol = ni * 16 + lm;
                    #pragma unroll
                    for (int rr = 0; rr < 4; ++rr) {
                        int tloc = w * 16 + quad * 4 + rr;
                        S[ni][rr] = (scol > tloc) ? -INFINITY : S[ni][rr] * 0.125f;
                    }
                }
            } else {
                #pragma unroll
                for (int ni = 0; ni < 4; ++ni)
                    #pragma unroll
                    for (int rr = 0; rr < 4; ++rr)
                        S[ni][rr] *= 0.125f;
            }
            float alpha[4];
            #pragma unroll
            for (int rr = 0; rr < 4; ++rr) {
                float mx = fmaxf(fmaxf(S[0][rr], S[1][rr]), fmaxf(S[2][rr], S[3][rr]));
                mx = fmaxf(mx, __shfl_xor(mx, 1));
                mx = fmaxf(mx, __shfl_xor(mx, 2));
                mx = fmaxf(mx, __shfl_xor(mx, 4));
                mx = fmaxf(mx, __shfl_xor(mx, 8));
                float mnew = fmaxf(mr[rr], mx);
                alpha[rr] = __expf(mr[rr] - mnew);
                mr[rr] = mnew;
            }
            float rs[4] = {0.f, 0.f, 0.f, 0.f};
            #pragma unroll
            for (int ni = 0; ni < 4; ++ni) {
                #pragma unroll
                for (int rr = 0; rr < 4; ++rr) {
                    float p = __expf(S[ni][rr] - mr[rr]);
                    rs[rr] += p;
                    int addr = ((rr & 1) ? pw_odd : pw_even) + (rr * 4 + ni) * 64;
                    lds[addr] = f2bf(p);
                }
            }
            #pragma unroll
            for (int rr = 0; rr < 4; ++rr) {
                float s = rs[rr];
                s += __shfl_xor(s, 1);
                s += __shfl_xor(s, 2);
                s += __shfl_xor(s, 4);
                s += __shfl_xor(s, 8);
                lr[rr] = lr[rr] * alpha[rr] + s;
                O[0][rr] *= alpha[rr]; O[1][rr] *= alpha[rr];
                O[2][rr] *= alpha[rr]; O[3][rr] *= alpha[rr];
            }
            __syncthreads();   // P write -> read ordering
            short8 pa0 = *(const short8*)(lds + pr0);
            short8 pa1 = *(const short8*)(lds + pr0 + 128);
            #pragma unroll
            for (int nd = 0; nd < 4; ++nd) {
                O[nd] = __builtin_amdgcn_mfma_f32_16x16x32_bf16(pa0, vb[nd][0], O[nd], 0, 0, 0);
                O[nd] = __builtin_amdgcn_mfma_f32_16x16x32_bf16(pa1, vb[nd][1], O[nd], 0, 0, 0);
            }
        }
        #pragma unroll
        for (int rr = 0; rr < 4; ++rr) {
            float inv = 1.0f / lr[rr];
            int t = t0 + quad * 4 + rr;
            u16* op = attn + (size_t)(b * 256 + t) * 512 + h * 64 + lm;
            op[0]  = f2bf(O[0][rr] * inv);
            op[16] = f2bf(O[1][rr] * inv);
            op[32] = f2bf(O[2][rr] * inv);
            op[48] = f2bf(O[3][rr] * inv);
        }
    }
}

extern "C" void kernel_launch(void* const* d_in, const int* in_sizes, int n_in,
                              void* d_out, int out_size, void* d_ws, size_t ws_size,
                              hipStream_t stream) {
    const float* x  = (const float*)d_in[0];
    const float* wq = (const float*)d_in[1];
    const float* wk = (const float*)d_in[2];
    const float* wv = (const float*)d_in[3];
    const float* bq = (const float*)d_in[4];
    const float* bk = (const float*)d_in[5];
    const float* bv = (const float*)d_in[6];
    const float* wo = (const float*)d_in[7];
    const float* bo = (const float*)d_in[8];
    float* out = (float*)d_out;

    char* ws = (char*)d_ws;
    const size_t SZ = 16777216;                  // 16384*512*2 bytes
    u16* xb    = (u16*)(ws);
    u16* Qb    = (u16*)(ws + SZ);
    u16* Kb    = (u16*)(ws + 2 * SZ);
    u16* Vt    = (u16*)(ws + 3 * SZ);            // [head][d][t]
    u16* attn  = (u16*)(ws + 4 * SZ);
    u16* wqkvT = (u16*)(ws + 5 * SZ);
    u16* woT   = (u16*)(ws + 5 * SZ + 1572864);

    cast_x_kernel<<<8192, 256, 0, stream>>>(x, xb);
    pack_wqkv_kernel<<<3072, 256, 0, stream>>>(wq, wk, wv, wqkvT);
    pack_wo_kernel<<<1024, 256, 0, stream>>>(wo, woT);

    gemm128_kernel<0, 12><<<1536, 256, 0, stream>>>(
        xb, wqkvT, nullptr, nullptr, Qb, Kb, Vt, bq, bk, bv);

    attn_mfma_kernel<<<1024, 256, 0, stream>>>(Qb, Kb, Vt, attn);

    gemm128_kernel<1, 4><<<512, 256, 0, stream>>>(
        attn, woT, out, bo, nullptr, nullptr, nullptr, nullptr, nullptr, nullptr);
}

// Round 11
// 204.559 us; speedup vs baseline: 1.4727x; 1.0542x over previous
//
#include <hip/hip_runtime.h>

typedef unsigned int   u32;
typedef unsigned short u16;
typedef __attribute__((ext_vector_type(8))) short short8;
typedef __attribute__((ext_vector_type(4))) float f32x4;

// B=64 T=256 C=512 H=8 D=64; M = B*T = 16384; K = 512; Nqkv = 1536

__device__ __forceinline__ u16 f2bf(float f) {
    u32 u = __float_as_uint(f);
    u += 0x7fffu + ((u >> 16) & 1u);   // RNE
    return (u16)(u >> 16);
}

// async global->LDS 16B DMA; LDS dest must be wave-uniform base + lane*16.
__device__ __forceinline__ void gload_lds16(const u16* g, u16* l) {
    __builtin_amdgcn_global_load_lds(
        (const __attribute__((address_space(1))) u32*)(const void*)g,
        (__attribute__((address_space(3))) u32*)(void*)l, 16, 0, 0);
}

// ---------------- cast x (fp32 -> bf16) ----------------
__global__ void cast_x_kernel(const float* __restrict__ x, u16* __restrict__ xb) {
    int i = blockIdx.x * 256 + threadIdx.x;
    float4 v = ((const float4*)x)[i];
    ushort4 o;
    o.x = f2bf(v.x); o.y = f2bf(v.y); o.z = f2bf(v.z); o.w = f2bf(v.w);
    ((ushort4*)xb)[i] = o;
}

// -------- pack wq|wk|wv -> bf16 [1536][512] transposed --------
__global__ void pack_wqkv_kernel(const float* __restrict__ wq, const float* __restrict__ wk,
                                 const float* __restrict__ wv, u16* __restrict__ wt) {
    int i = blockIdx.x * 256 + threadIdx.x;
    int n = i >> 9, c = i & 511;
    int proj = n >> 9, hd = n & 511;
    int h = hd >> 6, d = hd & 63;
    const float* w = (proj == 0) ? wq : (proj == 1) ? wk : wv;
    wt[(size_t)n * 512 + c] = f2bf(w[h * 32768 + c * 64 + d]);
}

// -------- pack wo [512][512] -> bf16 transposed [n][k] --------
__global__ void pack_wo_kernel(const float* __restrict__ wo, u16* __restrict__ wt) {
    int i = blockIdx.x * 256 + threadIdx.x;
    int n = i >> 9, k = i & 511;
    wt[(size_t)n * 512 + k] = f2bf(wo[(size_t)k * 512 + n]);
}

// ---------------- 128x128 bf16 MFMA GEMM, K=512, TN, BK=64 ----------------
// R10 post-mortem: per-block-iter cost is a ~1800-cyc constant dominated by the
// vmcnt(0) DMA-drain latency (m102 cross-check: same structure, 1 block/CU,
// ~2000 cyc/iter) — invariant to staging flavor and residency. Lever: FEWER
// drains. BK=64 -> 8 k-iters (was 16), same total bytes/MFMAs, dbuf 64KB LDS.
// Staging map (conflict-free, verified): call j stages row r=j*32+w*8+(l>>3),
// 16B-chunk slot=l&7, global chunk c=slot^(r&7)=(l&7)^((l>>3)&7); LDS dest =
// wave base + lane*16 (DMA requirement). Fragment reads: row stride 128B,
// slot=((h*4+quad)^(lm&7)) -> every in-order 8-lane group covers all 8 bank
// groups (reads AND writes). XCD swizzle: XCD x owns m-stripes for all NT
// n-tiles (A once/XCD, B L2-resident).
template<int EPI, int NT>
__global__ __launch_bounds__(256)
void gemm128_kernel(const u16* __restrict__ A, const u16* __restrict__ Bt,
                    float* __restrict__ outf, const float* __restrict__ bo,
                    u16* __restrict__ Qb, u16* __restrict__ Kb, u16* __restrict__ Vb,
                    const float* __restrict__ bq, const float* __restrict__ bk,
                    const float* __restrict__ bv) {
    __shared__ __align__(16) u16 As[2][8192];   // 128 rows x 64 k, 16KB per buffer
    __shared__ __align__(16) u16 Bs[2][8192];
    const int tid = threadIdx.x;
    const int bid = blockIdx.x;
    const int xcd = bid & 7;
    const int k8  = bid >> 3;                 // 0 .. 16*NT-1
    const int m0 = (xcd * 16 + k8 / NT) * 128;
    const int n0 = (k8 % NT) * 128;
    const int w = tid >> 6, lane = tid & 63;
    const int srow = w * 8 + (lane >> 3);               // + j*32
    const int sc   = (lane & 7) ^ ((lane >> 3) & 7);    // global 16B-chunk
    const u16* Ag = A  + (size_t)(m0 + srow) * 512 + sc * 8;
    const u16* Bg = Bt + (size_t)(n0 + srow) * 512 + sc * 8;
    const int lofs = w * 512 + lane * 8;                // + j*2048 (u16 units)

    const int wrow = (w >> 1) * 64, wcol = (w & 1) * 64;
    const int lm = lane & 15, quad = lane >> 4;
    const int l7 = lm & 7;

    f32x4 acc[4][4] = {};

    // prologue: stage tile 0 into buffer 0
    #pragma unroll
    for (int j = 0; j < 4; ++j) {
        gload_lds16(Ag + j * (32 * 512), As[0] + j * 2048 + lofs);
        gload_lds16(Bg + j * (32 * 512), Bs[0] + j * 2048 + lofs);
    }

    #pragma unroll 1
    for (int kt = 0; kt < 8; ++kt) {
        __syncthreads();   // tile kt DMA complete; other buffer's old reads done
        if (kt < 7) {      // prefetch tile kt+1
            const u16* Agp = Ag + (kt + 1) * 64;
            const u16* Bgp = Bg + (kt + 1) * 64;
            u16* Asp = As[(kt + 1) & 1] + lofs;
            u16* Bsp = Bs[(kt + 1) & 1] + lofs;
            #pragma unroll
            for (int j = 0; j < 4; ++j) {
                gload_lds16(Agp + j * (32 * 512), Asp + j * 2048);
                gload_lds16(Bgp + j * (32 * 512), Bsp + j * 2048);
            }
        }
        const u16* Ac = As[kt & 1];
        const u16* Bc = Bs[kt & 1];
        short8 af[2][4], bf[2][4];
        #pragma unroll
        for (int h = 0; h < 2; ++h) {
            const int slot = ((h * 4 + quad) ^ l7) * 8;
            #pragma unroll
            for (int mi = 0; mi < 4; ++mi)
                af[h][mi] = *(const short8*)(Ac + (wrow + mi * 16 + lm) * 64 + slot);
            #pragma unroll
            for (int ni = 0; ni < 4; ++ni)
                bf[h][ni] = *(const short8*)(Bc + (wcol + ni * 16 + lm) * 64 + slot);
        }
        #pragma unroll
        for (int h = 0; h < 2; ++h)
            #pragma unroll
            for (int mi = 0; mi < 4; ++mi)
                #pragma unroll
                for (int ni = 0; ni < 4; ++ni)
                    acc[mi][ni] = __builtin_amdgcn_mfma_f32_16x16x32_bf16(af[h][mi], bf[h][ni], acc[mi][ni], 0, 0, 0);
    }

    if (EPI == 1) {
        #pragma unroll
        for (int ni = 0; ni < 4; ++ni) {
            int ncol = n0 + wcol + ni * 16 + lm;
            float bias = bo[ncol];
            #pragma unroll
            for (int mi = 0; mi < 4; ++mi) {
                int mbase = m0 + wrow + mi * 16 + quad * 4;
                #pragma unroll
                for (int r = 0; r < 4; ++r)
                    outf[(size_t)(mbase + r) * 512 + ncol] = acc[mi][ni][r] + bias;
            }
        }
    } else {
        #pragma unroll
        for (int ni = 0; ni < 4; ++ni) {
            int ncol = n0 + wcol + ni * 16 + lm;
            int proj = ncol >> 9, hd = ncol & 511;
            int h = hd >> 6, d = hd & 63;
            const float* bptr = (proj == 0) ? bq : (proj == 1) ? bk : bv;
            u16* dst = (proj == 0) ? Qb : (proj == 1) ? Kb : Vb;
            float bias = bptr[hd];
            #pragma unroll
            for (int mi = 0; mi < 4; ++mi) {
                int mbase = m0 + wrow + mi * 16 + quad * 4;
                #pragma unroll
                for (int r = 0; r < 4; ++r) {
                    int mrow = mbase + r;
                    int b = mrow >> 8, t = mrow & 255;
                    size_t idx = (proj == 2)
                        ? ((size_t)((b * 8 + h) * 64 + d) * 256 + t)     // Vt [head][d][t]
                        : ((size_t)((b * 8 + h) * 256 + t) * 64 + d);   // Q/K [head][t][d]
                    dst[idx] = f2bf(acc[mi][ni][r] + bias);
                }
            }
        }
    }
}

// ---------------- MFMA flash attention (unchanged from R10 config) ----------
// TWO wgs per (b,h) (iset 0: i in {0,3}; iset 1: i in {1,2}), XCD-co-located.
// K staged in LDS (XOR 16B-chunk swizzle, conflict-free); V fragments read
// directly from global Vt[head][d][t], hoisted above softmax. LDS 40KB/wg.
__global__ __launch_bounds__(256)
void attn_mfma_kernel(const u16* __restrict__ Qg, const u16* __restrict__ Kg,
                      const u16* __restrict__ Vtg, u16* __restrict__ attn) {
    __shared__ __align__(16) u16 lds[20480];   // K:0..16383 | P: 16384 + w*1024
    const int bid = blockIdx.x;
    const int head = (bid & 7) * 64 + ((bid >> 3) >> 1);
    const int iset = (bid >> 3) & 1;
    const int b = head >> 3, h = head & 7;
    const int tid = threadIdx.x;
    const size_t hb = (size_t)head * 16384;

    {
        const uint4* Ksrc = (const uint4*)(Kg + hb);
        uint4* L4 = (uint4*)lds;
        #pragma unroll
        for (int it = 0; it < 8; ++it) {
            int g = it * 256 + tid;
            int kr = g >> 3, kc = g & 7;
            L4[kr * 8 + (kc ^ (kr & 7))] = Ksrc[g];
        }
    }
    __syncthreads();

    const int w = tid >> 6, lane = tid & 63;
    const int lm = lane & 15, quad = lane >> 4;
    const int l7 = lm & 7;

    const int kx0 = (quad ^ l7) * 8;
    const int kx1 = ((4 + quad) ^ l7) * 8;
    const u16* Kbase = lds + lm * 64;
    const u16* Vg = Vtg + hb;
    const int Pbase = 16384 + w * 1024;
    const int x0 = (lm >> 3) & 1;
    const int pw_even = Pbase + quad * 16 + l7 + x0 * 8;
    const int pw_odd  = Pbase + quad * 16 + l7 + (x0 ^ 1) * 8;
    const int pr0 = Pbase + ((lm & 3) * 4 + (quad >> 1)) * 64
                  + (2 * (lm >> 2) + ((quad & 1) ^ (lm & 1))) * 8;

    #pragma unroll 1
    for (int ii = 0; ii < 2; ++ii) {
        const int i = iset ? (ii ? 2 : 1) : (ii ? 3 : 0);
        const int t0 = i * 64 + w * 16;
        short8 qa0 = *(const short8*)(Qg + hb + (size_t)(t0 + lm) * 64 + quad * 8);
        short8 qa1 = *(const short8*)(Qg + hb + (size_t)(t0 + lm) * 64 + 32 + quad * 8);
        f32x4 O[4] = {};
        float mr[4] = {-INFINITY, -INFINITY, -INFINITY, -INFINITY};
        float lr[4] = {0.f, 0.f, 0.f, 0.f};

        #pragma unroll 1
        for (int j = 0; j <= i; ++j) {
            f32x4 S[4] = {};
            #pragma unroll
            for (int ni = 0; ni < 4; ++ni) {
                const u16* kp = Kbase + j * 4096 + ni * 1024;
                short8 kb0 = *(const short8*)(kp + kx0);
                short8 kb1 = *(const short8*)(kp + kx1);
                S[ni] = __builtin_amdgcn_mfma_f32_16x16x32_bf16(qa0, kb0, S[ni], 0, 0, 0);
                S[ni] = __builtin_amdgcn_mfma_f32_16x16x32_bf16(qa1, kb1, S[ni], 0, 0, 0);
            }
            // hoisted V-fragment loads (P-independent; overlap softmax+barrier)
            short8 vb[4][2];
            #pragma unroll
            for (int nd = 0; nd < 4; ++nd) {
                const u16* vp = Vg + (size_t)(nd * 16 + lm) * 256 + j * 64;
                vb[nd][0] = *(const short8*)(vp + quad * 8);
                vb[nd][1] = *(const short8*)(vp + 32 + quad * 8);
            }
            if (j == i) {
                #pragma unroll
                for (int ni = 0; ni < 4; ++ni) {
                    int scol = ni * 16 + lm;
                    #pragma unroll
                    for (int rr = 0; rr < 4; ++rr) {
                        int tloc = w * 16 + quad * 4 + rr;
                        S[ni][rr] = (scol > tloc) ? -INFINITY : S[ni][rr] * 0.125f;
                    }
                }
            } else {
                #pragma unroll
                for (int ni = 0; ni < 4; ++ni)
                    #pragma unroll
                    for (int rr = 0; rr < 4; ++rr)
                        S[ni][rr] *= 0.125f;
            }
            float alpha[4];
            #pragma unroll
            for (int rr = 0; rr < 4; ++rr) {
                float mx = fmaxf(fmaxf(S[0][rr], S[1][rr]), fmaxf(S[2][rr], S[3][rr]));
                mx = fmaxf(mx, __shfl_xor(mx, 1));
                mx = fmaxf(mx, __shfl_xor(mx, 2));
                mx = fmaxf(mx, __shfl_xor(mx, 4));
                mx = fmaxf(mx, __shfl_xor(mx, 8));
                float mnew = fmaxf(mr[rr], mx);
                alpha[rr] = __expf(mr[rr] - mnew);
                mr[rr] = mnew;
            }
            float rs[4] = {0.f, 0.f, 0.f, 0.f};
            #pragma unroll
            for (int ni = 0; ni < 4; ++ni) {
                #pragma unroll
                for (int rr = 0; rr < 4; ++rr) {
                    float p = __expf(S[ni][rr] - mr[rr]);
                    rs[rr] += p;
                    int addr = ((rr & 1) ? pw_odd : pw_even) + (rr * 4 + ni) * 64;
                    lds[addr] = f2bf(p);
                }
            }
            #pragma unroll
            for (int rr = 0; rr < 4; ++rr) {
                float s = rs[rr];
                s += __shfl_xor(s, 1);
                s += __shfl_xor(s, 2);
                s += __shfl_xor(s, 4);
                s += __shfl_xor(s, 8);
                lr[rr] = lr[rr] * alpha[rr] + s;
                O[0][rr] *= alpha[rr]; O[1][rr] *= alpha[rr];
                O[2][rr] *= alpha[rr]; O[3][rr] *= alpha[rr];
            }
            __syncthreads();   // P write -> read ordering
            short8 pa0 = *(const short8*)(lds + pr0);
            short8 pa1 = *(const short8*)(lds + pr0 + 128);
            #pragma unroll
            for (int nd = 0; nd < 4; ++nd) {
                O[nd] = __builtin_amdgcn_mfma_f32_16x16x32_bf16(pa0, vb[nd][0], O[nd], 0, 0, 0);
                O[nd] = __builtin_amdgcn_mfma_f32_16x16x32_bf16(pa1, vb[nd][1], O[nd], 0, 0, 0);
            }
        }
        #pragma unroll
        for (int rr = 0; rr < 4; ++rr) {
            float inv = 1.0f / lr[rr];
            int t = t0 + quad * 4 + rr;
            u16* op = attn + (size_t)(b * 256 + t) * 512 + h * 64 + lm;
            op[0]  = f2bf(O[0][rr] * inv);
            op[16] = f2bf(O[1][rr] * inv);
            op[32] = f2bf(O[2][rr] * inv);
            op[48] = f2bf(O[3][rr] * inv);
        }
    }
}

extern "C" void kernel_launch(void* const* d_in, const int* in_sizes, int n_in,
                              void* d_out, int out_size, void* d_ws, size_t ws_size,
                              hipStream_t stream) {
    const float* x  = (const float*)d_in[0];
    const float* wq = (const float*)d_in[1];
    const float* wk = (const float*)d_in[2];
    const float* wv = (const float*)d_in[3];
    const float* bq = (const float*)d_in[4];
    const float* bk = (const float*)d_in[5];
    const float* bv = (const float*)d_in[6];
    const float* wo = (const float*)d_in[7];
    const float* bo = (const float*)d_in[8];
    float* out = (float*)d_out;

    char* ws = (char*)d_ws;
    const size_t SZ = 16777216;                  // 16384*512*2 bytes
    u16* xb    = (u16*)(ws);
    u16* Qb    = (u16*)(ws + SZ);
    u16* Kb    = (u16*)(ws + 2 * SZ);
    u16* Vt    = (u16*)(ws + 3 * SZ);            // [head][d][t]
    u16* attn  = (u16*)(ws + 4 * SZ);
    u16* wqkvT = (u16*)(ws + 5 * SZ);
    u16* woT   = (u16*)(ws + 5 * SZ + 1572864);

    cast_x_kernel<<<8192, 256, 0, stream>>>(x, xb);
    pack_wqkv_kernel<<<3072, 256, 0, stream>>>(wq, wk, wv, wqkvT);
    pack_wo_kernel<<<1024, 256, 0, stream>>>(wo, woT);

    gemm128_kernel<0, 12><<<1536, 256, 0, stream>>>(
        xb, wqkvT, nullptr, nullptr, Qb, Kb, Vt, bq, bk, bv);

    attn_mfma_kernel<<<1024, 256, 0, stream>>>(Qb, Kb, Vt, attn);

    gemm128_kernel<1, 4><<<512, 256, 0, stream>>>(
        attn, woT, out, bo, nullptr, nullptr, nullptr, nullptr, nullptr, nullptr);
}